// Round 1
// baseline (6096.857 us; speedup 1.0000x reference)
//
#include <hip/hip_runtime.h>
#include <math.h>

// Spectral regularization: 1e-4 * (sigma_max(w1) + sigma_max(w2) + sigma_max(w3))
// via Lanczos on B = A^T A (no reorthogonalization), K steps, then Sturm bisection
// on the tridiagonal for lambda_max.
//
// Matrix shapes (row-major [rows, cols]):
//   w1: 4096 x 4096, w2: 8192 x 2048, w3: 2048 x 8192

#define K_STEPS 64
#define VCAP 8192

__device__ __forceinline__ int matM(int m) { return m == 0 ? 4096 : (m == 1 ? 8192 : 2048); }
__device__ __forceinline__ int matN(int m) { return m == 0 ? 4096 : (m == 1 ? 2048 : 8192); }

// ws layout (floats):
//  [0*VCAP .. )  V0  (3 * VCAP)   v_{j-1}
//  [3*VCAP .. )  V1  (3 * VCAP)   v_j
//  [6*VCAP .. )  W   (3 * VCAP)   w = A v
//  [9*VCAP .. )  Z   (3 * VCAP)   z = A^T w (atomic-accumulated; zeroed by k_update/k_init)
//  [12*VCAP .. ) ALPHA (3 * K_STEPS), then BETA (3 * K_STEPS)

__device__ float blockReduce(float v) {
    __shared__ float sh[16];
    int lane = threadIdx.x & 63, wid = threadIdx.x >> 6;
#pragma unroll
    for (int off = 32; off; off >>= 1) v += __shfl_down(v, off, 64);
    if (lane == 0) sh[wid] = v;
    __syncthreads();
    if (wid == 0) {
        int nw = (blockDim.x + 63) >> 6;
        float x = (lane < nw) ? sh[lane] : 0.0f;
#pragma unroll
        for (int off = 8; off; off >>= 1) x += __shfl_down(x, off, 64);
        if (lane == 0) sh[0] = x;
    }
    __syncthreads();
    float r = sh[0];
    __syncthreads();  // protect sh for next call
    return r;
}

__global__ __launch_bounds__(1024) void k_init(float* ws) {
    int mat = blockIdx.x;
    int n = matN(mat);
    float* V0 = ws + mat * VCAP;
    float* V1 = ws + 3 * VCAP + mat * VCAP;
    float* Z  = ws + 9 * VCAP + mat * VCAP;
    int tid = threadIdx.x;
    float acc = 0.0f;
    for (int i = tid; i < VCAP; i += 1024) {
        float val = 0.0f;
        if (i < n) {
            unsigned h = (unsigned)(i * 2654435761u) ^ (0x9E3779B9u * (unsigned)(mat + 1));
            h ^= h >> 16; h *= 0x85EBCA6Bu; h ^= h >> 13; h *= 0xC2B2AE35u; h ^= h >> 16;
            val = ((h >> 8) * (1.0f / 16777216.0f)) - 0.5f;
            acc += val * val;
        }
        V1[i] = val; V0[i] = 0.0f; Z[i] = 0.0f;
    }
    float nrm2 = blockReduce(acc);
    float inv = rsqrtf(nrm2);
    for (int i = tid; i < n; i += 1024) V1[i] *= inv;
}

// W = A * V1, one wave per row
__global__ __launch_bounds__(256) void k_gemvA(const float* __restrict__ A0,
                                               const float* __restrict__ A1,
                                               const float* __restrict__ A2,
                                               float* __restrict__ ws) {
    const float* V1 = ws + 3 * VCAP;
    float* W = ws + 6 * VCAP;
    int wid = (int)((blockIdx.x * blockDim.x + threadIdx.x) >> 6);
    int lane = threadIdx.x & 63;
    int mat, row;
    if (wid < 4096)       { mat = 0; row = wid; }
    else if (wid < 12288) { mat = 1; row = wid - 4096; }
    else                  { mat = 2; row = wid - 12288; }
    const float* A = mat == 0 ? A0 : (mat == 1 ? A1 : A2);
    int n = matN(mat);
    const float4* rowp = (const float4*)(A + (size_t)row * n);
    const float4* vp = (const float4*)(V1 + mat * VCAP);
    int nf4 = n >> 2;
    float s = 0.0f;
    for (int t = lane; t < nf4; t += 64) {
        float4 a = rowp[t], v = vp[t];
        s += a.x * v.x + a.y * v.y + a.z * v.z + a.w * v.w;
    }
#pragma unroll
    for (int off = 32; off; off >>= 1) s += __shfl_down(s, off, 64);
    if (lane == 0) W[mat * VCAP + row] = s;
}

// Z += A^T * W. 256 blocks per matrix: tiles of (64 rows x 1024 cols).
// Each thread handles 4 consecutive cols; partials atomicAdd'ed to Z.
__global__ __launch_bounds__(256) void k_gemvT(const float* __restrict__ A0,
                                               const float* __restrict__ A1,
                                               const float* __restrict__ A2,
                                               float* __restrict__ ws) {
    const float* W = ws + 6 * VCAP;
    float* Z = ws + 9 * VCAP;
    int bid = blockIdx.x;
    int mat = bid >> 8;           // 256 blocks per matrix
    int t = bid & 255;
    int n = matN(mat), m = matM(mat);
    int nColTiles = n >> 10;      // tiles of 1024 cols: 4 / 2 / 8
    int colTile = t % nColTiles;
    int rowChunk = t / nColTiles; // chunks of 64 rows: 64 / 128 / 32
    int r0 = rowChunk * 64;
    int col = colTile * 1024 + threadIdx.x * 4;
    const float* A = mat == 0 ? A0 : (mat == 1 ? A1 : A2);
    __shared__ float wsh[64];
    if (threadIdx.x < 64) wsh[threadIdx.x] = W[mat * VCAP + r0 + threadIdx.x];
    __syncthreads();
    const float* Ab = A + (size_t)r0 * n + col;
    float4 s = {0.0f, 0.0f, 0.0f, 0.0f};
#pragma unroll 4
    for (int r = 0; r < 64; ++r) {
        float4 a = *(const float4*)(Ab + (size_t)r * n);
        float w = wsh[r];
        s.x += a.x * w; s.y += a.y * w; s.z += a.z * w; s.w += a.w * w;
    }
    float* Zm = Z + mat * VCAP + col;
    atomicAdd(Zm + 0, s.x);
    atomicAdd(Zm + 1, s.y);
    atomicAdd(Zm + 2, s.z);
    atomicAdd(Zm + 3, s.w);
}

// alpha = v.z ; r = z - alpha v - beta_prev v_prev ; beta = ||r|| ; v_next = r/beta
__global__ __launch_bounds__(1024) void k_update(float* __restrict__ ws, int j) {
    int mat = blockIdx.x;
    int n = matN(mat);
    float* V0 = ws + mat * VCAP;
    float* V1 = ws + 3 * VCAP + mat * VCAP;
    float* Z  = ws + 9 * VCAP + mat * VCAP;
    float* ALPHA = ws + 12 * VCAP;
    float* BETA  = ALPHA + 3 * K_STEPS;
    int tid = threadIdx.x;

    float acc = 0.0f;
    for (int i = tid; i < n; i += 1024) acc += V1[i] * Z[i];
    float alpha = blockReduce(acc);

    float bp = (j > 0) ? BETA[mat * K_STEPS + j - 1] : 0.0f;
    float acc2 = 0.0f;
    for (int i = tid; i < n; i += 1024) {
        float v1 = V1[i];
        float r = Z[i] - alpha * v1 - bp * V0[i];
        V0[i] = v1;
        Z[i] = r;
        acc2 += r * r;
    }
    float b2 = blockReduce(acc2);
    float beta = sqrtf(b2);
    float inv = (beta > 1e-20f) ? (1.0f / beta) : 0.0f;
    for (int i = tid; i < n; i += 1024) {
        V1[i] = Z[i] * inv;
        Z[i] = 0.0f;  // ready for next step's atomic accumulation
    }
    if (tid == 0) {
        ALPHA[mat * K_STEPS + j] = alpha;
        BETA[mat * K_STEPS + j] = beta;
    }
}

// lambda_max of each K x K tridiagonal via Sturm bisection (fp64), sum sqrt, scale.
__global__ void k_final(const float* __restrict__ ws, float* __restrict__ out) {
    __shared__ double sig[3];
    int tid = threadIdx.x;
    if (tid < 3) {
        const float* ALPHA = ws + 12 * VCAP + tid * K_STEPS;
        const float* BETA  = ws + 12 * VCAP + 3 * K_STEPS + tid * K_STEPS;
        double a[K_STEPS], b[K_STEPS];
        for (int i = 0; i < K_STEPS; ++i) { a[i] = ALPHA[i]; b[i] = BETA[i]; }
        double hi = 0.0, lo = 0.0;
        for (int i = 0; i < K_STEPS; ++i) {
            double bl = i ? b[i - 1] : 0.0;
            double br = (i < K_STEPS - 1) ? b[i] : 0.0;
            double g = a[i] + bl + br;
            if (g > hi) hi = g;
        }
        for (int it = 0; it < 200 && (hi - lo) > 1e-9 * hi; ++it) {
            double mid = 0.5 * (lo + hi);
            int cnt = 0;
            double d = 1.0;
            for (int i = 0; i < K_STEPS; ++i) {
                double off = i ? (b[i - 1] * b[i - 1]) / d : 0.0;
                d = (a[i] - mid) - off;
                if (d == 0.0) d = -1e-300;
                if (d < 0.0) cnt++;
            }
            if (cnt == K_STEPS) hi = mid; else lo = mid;
        }
        double lam = 0.5 * (lo + hi);
        sig[tid] = sqrt(lam > 0.0 ? lam : 0.0);
    }
    __syncthreads();
    if (tid == 0) out[0] = (float)(1e-4 * (sig[0] + sig[1] + sig[2]));
}

extern "C" void kernel_launch(void* const* d_in, const int* in_sizes, int n_in,
                              void* d_out, int out_size, void* d_ws, size_t ws_size,
                              hipStream_t stream) {
    const float* A0 = (const float*)d_in[0];
    const float* A1 = (const float*)d_in[1];
    const float* A2 = (const float*)d_in[2];
    float* ws = (float*)d_ws;
    float* out = (float*)d_out;

    hipLaunchKernelGGL(k_init, dim3(3), dim3(1024), 0, stream, ws);
    for (int j = 0; j < K_STEPS; ++j) {
        hipLaunchKernelGGL(k_gemvA, dim3(3584), dim3(256), 0, stream, A0, A1, A2, ws);
        hipLaunchKernelGGL(k_gemvT, dim3(768), dim3(256), 0, stream, A0, A1, A2, ws);
        hipLaunchKernelGGL(k_update, dim3(3), dim3(1024), 0, stream, ws, j);
    }
    hipLaunchKernelGGL(k_final, dim3(1), dim3(64), 0, stream, ws, out);
}

// Round 2
// 5964.227 us; speedup vs baseline: 1.0222x; 1.0222x over previous
//
#include <hip/hip_runtime.h>
#include <math.h>

// Spectral regularization: 1e-4 * (sigma_max(w1) + sigma_max(w2) + sigma_max(w3))
// Lanczos (K steps, no reorth) on B = A^T A, matrices converted once to bf16
// (fits in 256 MB L3 -> fast re-reads), then 64-lane parallel Sturm bisection.
//
// Shapes (row-major): w1 4096x4096, w2 8192x2048, w3 2048x8192 (each 16777216 elems)

#define K_STEPS 64
#define VCAP 8192
#define MELEMS 16777216

typedef unsigned int u32;

__device__ __forceinline__ int matM(int m) { return m == 0 ? 4096 : (m == 1 ? 8192 : 2048); }
__device__ __forceinline__ int matN(int m) { return m == 0 ? 4096 : (m == 1 ? 2048 : 8192); }

// bf16 pair unpack from u32 (little-endian: low 16 = even elem)
__device__ __forceinline__ float bflo(u32 u) { return __uint_as_float(u << 16); }
__device__ __forceinline__ float bfhi(u32 u) { return __uint_as_float(u & 0xffff0000u); }

__device__ __forceinline__ unsigned short bf_rne(float f) {
    u32 u = __float_as_uint(f);
    u32 r = u + 0x7fffu + ((u >> 16) & 1u);
    return (unsigned short)(r >> 16);
}

// vector ws layout (floats), pointer `vec`:
//  [0*VCAP) V0 (3*VCAP)  v_{j-1}
//  [3*VCAP) V1 (3*VCAP)  v_j
//  [6*VCAP) W  (3*VCAP)  w = A v
//  [9*VCAP) Z  (3*VCAP)  z = A^T w (atomics; zeroed by init/update)
//  [12*VCAP) ALPHA (3*K), BETA (3*K)

__device__ float blockReduce(float v) {
    __shared__ float sh[16];
    int lane = threadIdx.x & 63, wid = threadIdx.x >> 6;
#pragma unroll
    for (int off = 32; off; off >>= 1) v += __shfl_down(v, off, 64);
    if (lane == 0) sh[wid] = v;
    __syncthreads();
    if (wid == 0) {
        int nw = (blockDim.x + 63) >> 6;
        float x = (lane < nw) ? sh[lane] : 0.0f;
#pragma unroll
        for (int off = 8; off; off >>= 1) x += __shfl_down(x, off, 64);
        if (lane == 0) sh[0] = x;
    }
    __syncthreads();
    float r = sh[0];
    __syncthreads();
    return r;
}

__global__ __launch_bounds__(1024) void k_init(float* vec) {
    int mat = blockIdx.x;
    int n = matN(mat);
    float* V0 = vec + mat * VCAP;
    float* V1 = vec + 3 * VCAP + mat * VCAP;
    float* Z  = vec + 9 * VCAP + mat * VCAP;
    int tid = threadIdx.x;
    float acc = 0.0f;
    for (int i = tid; i < VCAP; i += 1024) {
        float val = 0.0f;
        if (i < n) {
            unsigned h = (unsigned)(i * 2654435761u) ^ (0x9E3779B9u * (unsigned)(mat + 1));
            h ^= h >> 16; h *= 0x85EBCA6Bu; h ^= h >> 13; h *= 0xC2B2AE35u; h ^= h >> 16;
            val = ((h >> 8) * (1.0f / 16777216.0f)) - 0.5f;
            acc += val * val;
        }
        V1[i] = val; V0[i] = 0.0f; Z[i] = 0.0f;
    }
    float nrm2 = blockReduce(acc);
    float inv = rsqrtf(nrm2);
    for (int i = tid; i < n; i += 1024) V1[i] *= inv;
}

// fp32 -> bf16 one-time conversion (all three matrices, blockIdx.y = mat)
__global__ __launch_bounds__(256) void k_convert(const float* __restrict__ A0,
                                                 const float* __restrict__ A1,
                                                 const float* __restrict__ A2,
                                                 unsigned short* __restrict__ B) {
    int mat = blockIdx.y;
    const float* A = mat == 0 ? A0 : (mat == 1 ? A1 : A2);
    unsigned short* Bm = B + (size_t)mat * MELEMS;
    int stride = gridDim.x * blockDim.x;
    const int nvec = MELEMS / 4;
    for (int i = blockIdx.x * blockDim.x + threadIdx.x; i < nvec; i += stride) {
        float4 a = ((const float4*)A)[i];
        ushort4 o;
        o.x = bf_rne(a.x); o.y = bf_rne(a.y); o.z = bf_rne(a.z); o.w = bf_rne(a.w);
        ((ushort4*)Bm)[i] = o;
    }
}

// ---------------- bf16 path ----------------
// W = A * V1, one wave per row
__global__ __launch_bounds__(256) void k_gemvA_bf(const unsigned short* __restrict__ B,
                                                  float* __restrict__ vec) {
    const float* V1 = vec + 3 * VCAP;
    float* W = vec + 6 * VCAP;
    int wid = (int)((blockIdx.x * blockDim.x + threadIdx.x) >> 6);
    int lane = threadIdx.x & 63;
    int mat, row;
    if (wid < 4096)       { mat = 0; row = wid; }
    else if (wid < 12288) { mat = 1; row = wid - 4096; }
    else                  { mat = 2; row = wid - 12288; }
    int n = matN(mat);
    const uint4* rp = (const uint4*)(B + (size_t)mat * MELEMS + (size_t)row * n);
    const float4* vp = (const float4*)(V1 + mat * VCAP);
    int nu = n >> 3;  // 8 bf16 per uint4
    float s = 0.0f;
    for (int t = lane; t < nu; t += 64) {
        uint4 a = rp[t];
        float4 v0 = vp[2 * t], v1 = vp[2 * t + 1];
        s += bflo(a.x) * v0.x + bfhi(a.x) * v0.y + bflo(a.y) * v0.z + bfhi(a.y) * v0.w
           + bflo(a.z) * v1.x + bfhi(a.z) * v1.y + bflo(a.w) * v1.z + bfhi(a.w) * v1.w;
    }
#pragma unroll
    for (int off = 32; off; off >>= 1) s += __shfl_down(s, off, 64);
    if (lane == 0) W[mat * VCAP + row] = s;
}

// Z += A^T * W. 128 blocks per matrix: (64 rows x 2048 cols) tiles, 8 cols/thread.
__global__ __launch_bounds__(256) void k_gemvT_bf(const unsigned short* __restrict__ B,
                                                  float* __restrict__ vec) {
    const float* W = vec + 6 * VCAP;
    float* Z = vec + 9 * VCAP;
    int bid = blockIdx.x;
    int mat = bid >> 7;   // 128 blocks per matrix
    int t = bid & 127;
    int n = matN(mat);
    int nCT = n >> 11;    // 2048-col tiles: 2 / 1 / 4
    int colTile = t % nCT;
    int rowChunk = t / nCT;
    int r0 = rowChunk * 64;
    int col = colTile * 2048 + threadIdx.x * 8;
    __shared__ float wsh[64];
    if (threadIdx.x < 64) wsh[threadIdx.x] = W[mat * VCAP + r0 + threadIdx.x];
    __syncthreads();
    const unsigned short* Ab = B + (size_t)mat * MELEMS + (size_t)r0 * n + col;
    float s0 = 0, s1 = 0, s2 = 0, s3 = 0, s4 = 0, s5 = 0, s6 = 0, s7 = 0;
#pragma unroll 8
    for (int r = 0; r < 64; ++r) {
        uint4 a = *(const uint4*)(Ab + (size_t)r * n);
        float w = wsh[r];
        s0 += bflo(a.x) * w; s1 += bfhi(a.x) * w;
        s2 += bflo(a.y) * w; s3 += bfhi(a.y) * w;
        s4 += bflo(a.z) * w; s5 += bfhi(a.z) * w;
        s6 += bflo(a.w) * w; s7 += bfhi(a.w) * w;
    }
    float* Zm = Z + mat * VCAP + col;
    atomicAdd(Zm + 0, s0); atomicAdd(Zm + 1, s1);
    atomicAdd(Zm + 2, s2); atomicAdd(Zm + 3, s3);
    atomicAdd(Zm + 4, s4); atomicAdd(Zm + 5, s5);
    atomicAdd(Zm + 6, s6); atomicAdd(Zm + 7, s7);
}

// ---------------- fp32 fallback path ----------------
__global__ __launch_bounds__(256) void k_gemvA(const float* __restrict__ A0,
                                               const float* __restrict__ A1,
                                               const float* __restrict__ A2,
                                               float* __restrict__ vec) {
    const float* V1 = vec + 3 * VCAP;
    float* W = vec + 6 * VCAP;
    int wid = (int)((blockIdx.x * blockDim.x + threadIdx.x) >> 6);
    int lane = threadIdx.x & 63;
    int mat, row;
    if (wid < 4096)       { mat = 0; row = wid; }
    else if (wid < 12288) { mat = 1; row = wid - 4096; }
    else                  { mat = 2; row = wid - 12288; }
    const float* A = mat == 0 ? A0 : (mat == 1 ? A1 : A2);
    int n = matN(mat);
    const float4* rowp = (const float4*)(A + (size_t)row * n);
    const float4* vp = (const float4*)(V1 + mat * VCAP);
    int nf4 = n >> 2;
    float s = 0.0f;
    for (int t = lane; t < nf4; t += 64) {
        float4 a = rowp[t], v = vp[t];
        s += a.x * v.x + a.y * v.y + a.z * v.z + a.w * v.w;
    }
#pragma unroll
    for (int off = 32; off; off >>= 1) s += __shfl_down(s, off, 64);
    if (lane == 0) W[mat * VCAP + row] = s;
}

__global__ __launch_bounds__(256) void k_gemvT(const float* __restrict__ A0,
                                               const float* __restrict__ A1,
                                               const float* __restrict__ A2,
                                               float* __restrict__ vec) {
    const float* W = vec + 6 * VCAP;
    float* Z = vec + 9 * VCAP;
    int bid = blockIdx.x;
    int mat = bid >> 8;
    int t = bid & 255;
    int n = matN(mat);
    int nColTiles = n >> 10;
    int colTile = t % nColTiles;
    int rowChunk = t / nColTiles;
    int r0 = rowChunk * 64;
    int col = colTile * 1024 + threadIdx.x * 4;
    const float* A = mat == 0 ? A0 : (mat == 1 ? A1 : A2);
    __shared__ float wsh[64];
    if (threadIdx.x < 64) wsh[threadIdx.x] = W[mat * VCAP + r0 + threadIdx.x];
    __syncthreads();
    const float* Ab = A + (size_t)r0 * n + col;
    float4 s = {0.0f, 0.0f, 0.0f, 0.0f};
#pragma unroll 4
    for (int r = 0; r < 64; ++r) {
        float4 a = *(const float4*)(Ab + (size_t)r * n);
        float w = wsh[r];
        s.x += a.x * w; s.y += a.y * w; s.z += a.z * w; s.w += a.w * w;
    }
    float* Zm = Z + mat * VCAP + col;
    atomicAdd(Zm + 0, s.x);
    atomicAdd(Zm + 1, s.y);
    atomicAdd(Zm + 2, s.z);
    atomicAdd(Zm + 3, s.w);
}

// alpha = v.z ; r = z - alpha v - beta_prev v_prev ; beta = ||r|| ; v_next = r/beta
__global__ __launch_bounds__(1024) void k_update(float* __restrict__ vec, int j) {
    int mat = blockIdx.x;
    int n = matN(mat);
    float* V0 = vec + mat * VCAP;
    float* V1 = vec + 3 * VCAP + mat * VCAP;
    float* Z  = vec + 9 * VCAP + mat * VCAP;
    float* ALPHA = vec + 12 * VCAP;
    float* BETA  = ALPHA + 3 * K_STEPS;
    int tid = threadIdx.x;

    float acc = 0.0f;
    for (int i = tid; i < n; i += 1024) acc += V1[i] * Z[i];
    float alpha = blockReduce(acc);

    float bp = (j > 0) ? BETA[mat * K_STEPS + j - 1] : 0.0f;
    float acc2 = 0.0f;
    for (int i = tid; i < n; i += 1024) {
        float v1 = V1[i];
        float r = Z[i] - alpha * v1 - bp * V0[i];
        V0[i] = v1;
        Z[i] = r;
        acc2 += r * r;
    }
    float b2 = blockReduce(acc2);
    float beta = sqrtf(b2);
    float inv = (beta > 1e-20f) ? (1.0f / beta) : 0.0f;
    for (int i = tid; i < n; i += 1024) {
        V1[i] = Z[i] * inv;
        Z[i] = 0.0f;
    }
    if (tid == 0) {
        ALPHA[mat * K_STEPS + j] = alpha;
        BETA[mat * K_STEPS + j] = beta;
    }
}

// lambda_max of each KxK tridiagonal: 64-lane parallel Sturm bisection,
// one wave per matrix, 4 rounds of 65-way interval split.
__global__ __launch_bounds__(256) void k_final2(const float* __restrict__ vec,
                                                float* __restrict__ out) {
    __shared__ double sa[3][K_STEPS], sb[3][K_STEPS];
    __shared__ double sig[3];
    int tid = threadIdx.x, wid = tid >> 6, lane = tid & 63;
    if (wid < 3) {
        const float* AL = vec + 12 * VCAP + wid * K_STEPS;
        const float* BE = vec + 12 * VCAP + 3 * K_STEPS + wid * K_STEPS;
        sa[wid][lane] = (double)AL[lane];
        sb[wid][lane] = (lane < K_STEPS - 1) ? (double)BE[lane] : 0.0;
    }
    __syncthreads();
    if (wid < 3) {
        // Gershgorin upper bound (wave-parallel max)
        double bl_ = lane ? sb[wid][lane - 1] : 0.0;
        double g = sa[wid][lane] + bl_ + sb[wid][lane];
#pragma unroll
        for (int off = 32; off; off >>= 1) {
            double o = __shfl_xor(g, off, 64);
            if (o > g) g = o;
        }
        double lo = 0.0, hi = g > 0.0 ? g : 1.0;
        for (int round = 0; round < 4; ++round) {
            double step = (hi - lo) / 65.0;
            double x = lo + step * (double)(lane + 1);
            int cnt = 0;
            double d = 1.0;
            for (int i = 0; i < K_STEPS; ++i) {
                double off2 = 0.0;
                if (i) { double b = sb[wid][i - 1]; off2 = b * b / d; }
                d = (sa[wid][i] - x) - off2;
                if (d == 0.0) d = -1e-300;
                if (d < 0.0) cnt++;
            }
            unsigned long long mask = __ballot(cnt >= K_STEPS);
            if (mask) {
                int idx = __ffsll(mask) - 1;
                hi = lo + step * (double)(idx + 1);
                lo = lo + step * (double)idx;
            } else {
                lo = lo + step * 64.0;
            }
        }
        if (lane == 0) {
            double lam = 0.5 * (lo + hi);
            sig[wid] = sqrt(lam > 0.0 ? lam : 0.0);
        }
    }
    __syncthreads();
    if (tid == 0) out[0] = (float)(1e-4 * (sig[0] + sig[1] + sig[2]));
}

extern "C" void kernel_launch(void* const* d_in, const int* in_sizes, int n_in,
                              void* d_out, int out_size, void* d_ws, size_t ws_size,
                              hipStream_t stream) {
    const float* A0 = (const float*)d_in[0];
    const float* A1 = (const float*)d_in[1];
    const float* A2 = (const float*)d_in[2];
    float* out = (float*)d_out;

    const size_t bf_bytes = (size_t)3 * MELEMS * 2;             // 100663296
    const size_t vec_bytes = (size_t)(12 * VCAP + 6 * K_STEPS) * 4;
    bool use_bf = ws_size >= bf_bytes + vec_bytes;

    unsigned short* B = (unsigned short*)d_ws;
    float* vec = use_bf ? (float*)((char*)d_ws + bf_bytes) : (float*)d_ws;

    hipLaunchKernelGGL(k_init, dim3(3), dim3(1024), 0, stream, vec);
    if (use_bf) {
        hipLaunchKernelGGL(k_convert, dim3(4096, 3), dim3(256), 0, stream, A0, A1, A2, B);
        for (int j = 0; j < K_STEPS; ++j) {
            hipLaunchKernelGGL(k_gemvA_bf, dim3(3584), dim3(256), 0, stream, B, vec);
            hipLaunchKernelGGL(k_gemvT_bf, dim3(384), dim3(256), 0, stream, B, vec);
            hipLaunchKernelGGL(k_update, dim3(3), dim3(1024), 0, stream, vec, j);
        }
    } else {
        for (int j = 0; j < K_STEPS; ++j) {
            hipLaunchKernelGGL(k_gemvA, dim3(3584), dim3(256), 0, stream, A0, A1, A2, vec);
            hipLaunchKernelGGL(k_gemvT, dim3(768), dim3(256), 0, stream, A0, A1, A2, vec);
            hipLaunchKernelGGL(k_update, dim3(3), dim3(1024), 0, stream, vec, j);
        }
    }
    hipLaunchKernelGGL(k_final2, dim3(1), dim3(256), 0, stream, vec, out);
}